// Round 1
// baseline (1779.450 us; speedup 1.0000x reference)
//
#include <hip/hip_runtime.h>
#include <hip/hip_bf16.h>
#include <cstdint>
#include <cstddef>

#define T_TOK 4096
#define HID   2048
#define INTER 768
#define NEXP  64

typedef float  f32x4  __attribute__((ext_vector_type(4)));
typedef __bf16 bf16x8 __attribute__((ext_vector_type(8)));
typedef __bf16 bf16x4 __attribute__((ext_vector_type(4)));

// ---------------- small helper kernels ----------------

__global__ void zero_meta_kernel(int* counts, int* fill) {
  int t = threadIdx.x;
  if (t < NEXP) { counts[t] = 0; fill[t] = 0; }
}

__global__ void scan_kernel(const int* __restrict__ counts, int* __restrict__ offsets) {
  if (threadIdx.x == 0) {
    int s = 0;
    for (int e = 0; e < NEXP; e++) { offsets[e] = s; s += counts[e]; }
    offsets[NEXP] = s;
  }
}

__global__ void scatter_kernel(const int* __restrict__ topk_id, const float* __restrict__ topk_w,
                               const int* __restrict__ offsets, int* __restrict__ fill,
                               int* __restrict__ pair_tok, float* __restrict__ pair_w) {
  int i = blockIdx.x * 256 + threadIdx.x;  // 0..32767
  int e = topk_id[i];
  int pos = offsets[e] + atomicAdd(&fill[e], 1);
  pair_tok[pos] = i >> 3;
  pair_w[pos]  = topk_w[i];
}

__global__ void cvt_kernel(const float* __restrict__ x, __bf16* __restrict__ xbf) {
  int i = blockIdx.x * 256 + threadIdx.x;  // T*H/4 threads
  float4 v = ((const float4*)x)[i];
  bf16x4 b;
  b[0] = (__bf16)v.x; b[1] = (__bf16)v.y; b[2] = (__bf16)v.z; b[3] = (__bf16)v.w;
  ((bf16x4*)xbf)[i] = b;
}

// ---------------- router: fp32 logits + wave-wide top-8 ----------------

__global__ __launch_bounds__(256) void router_kernel(
    const float* __restrict__ x, const float* __restrict__ gw,
    int* __restrict__ topk_id, float* __restrict__ topk_w, int* __restrict__ counts) {
  __shared__ float gs[64][65];
  __shared__ float xs[16][65];
  const int tid  = threadIdx.x;
  const int lane = tid & 63;
  const int wv   = tid >> 6;
  const int tblk = blockIdx.x * 16;

  float acc[4] = {0.f, 0.f, 0.f, 0.f};
  for (int kc = 0; kc < HID; kc += 64) {
    #pragma unroll
    for (int i = 0; i < 4; i++) {
      int r = tid >> 2;
      int c = (tid & 3) * 16 + i * 4;
      float4 v = *(const float4*)(gw + (size_t)r * HID + kc + c);
      gs[r][c + 0] = v.x; gs[r][c + 1] = v.y; gs[r][c + 2] = v.z; gs[r][c + 3] = v.w;
    }
    {
      int r = tid >> 4;
      int c = (tid & 15) * 4;
      float4 v = *(const float4*)(x + (size_t)(tblk + r) * HID + kc + c);
      xs[r][c + 0] = v.x; xs[r][c + 1] = v.y; xs[r][c + 2] = v.z; xs[r][c + 3] = v.w;
    }
    __syncthreads();
    #pragma unroll 8
    for (int k = 0; k < 64; k++) {
      float g = gs[lane][k];
      #pragma unroll
      for (int j = 0; j < 4; j++) acc[j] = fmaf(xs[wv * 4 + j][k], g, acc[j]);
    }
    __syncthreads();
  }

  for (int j = 0; j < 4; j++) {
    int t = tblk + wv * 4 + j;
    float vsel = acc[j];
    float m1 = 0.f, denom = 0.f;
    int myid = 0; float myw = 0.f;
    for (int s = 0; s < 8; s++) {
      float bv = vsel; int bi = lane;
      #pragma unroll
      for (int off = 32; off > 0; off >>= 1) {
        float ov = __shfl_xor(bv, off);
        int   oi = __shfl_xor(bi, off);
        if (ov > bv || (ov == bv && oi < bi)) { bv = ov; bi = oi; }
      }
      if (s == 0) m1 = bv;
      float ev = __expf(bv - m1);
      denom += ev;
      if (lane == s)  { myid = bi; myw = ev; }
      if (lane == bi) vsel = -3.402823466e38f;
    }
    if (lane < 8) {
      topk_id[t * 8 + lane] = myid;
      topk_w[t * 8 + lane]  = myw / denom;
      atomicAdd(&counts[myid], 1);
    }
  }
}

// ---------------- grouped GEMM1: x @ Wgu -> SwiGLU -> h (pair-weight folded) ----------------

__global__ __launch_bounds__(256) void gemm1_kernel(
    const __bf16* __restrict__ xbf, const float* __restrict__ wgu,
    const int* __restrict__ offsets, const int* __restrict__ pair_tok,
    const float* __restrict__ pair_w, __bf16* __restrict__ hbuf) {
  __shared__ __align__(16) char lsm[49152];
  char* lA = lsm;            // 128 rows x 64 k bf16, swizzled
  char* lB = lsm + 16384;    // 256 rows (gate 0..127, up 128..255) x 64 k bf16, swizzled

  const int e   = blockIdx.z;
  const int off = offsets[e];
  const int cnt = offsets[e + 1] - off;
  if (cnt <= 0) return;
  const int n0 = blockIdx.x * 128;
  const float* wbase = wgu + (size_t)e * HID * (2 * INTER);
  const int tid  = threadIdx.x;
  const int lane = tid & 63;
  const int w    = tid >> 6;
  const int wx = w & 1, wy = w >> 1;
  const int g  = lane >> 4;    // 0..3
  const int nq = lane & 15;    // 0..15

  for (int mt = blockIdx.y; mt * 128 < cnt; mt += (int)gridDim.y) {
    const int m0   = mt * 128;
    const int rows = min(128, cnt - m0);

    const __bf16* arow[4];
    #pragma unroll
    for (int i = 0; i < 4; i++) {
      int S = tid + i * 256;
      int r = S >> 3;
      int rr = (r < rows) ? r : 0;
      arow[i] = xbf + (size_t)pair_tok[off + m0 + rr] * HID;
    }

    f32x4 accg[4][4], accu[4][4];
    #pragma unroll
    for (int mi = 0; mi < 4; mi++)
      #pragma unroll
      for (int ni = 0; ni < 4; ni++)
        #pragma unroll
        for (int q = 0; q < 4; q++) { accg[mi][ni][q] = 0.f; accu[mi][ni][q] = 0.f; }

    for (int k0 = 0; k0 < HID; k0 += 64) {
      // stage A (bf16 gather rows)
      #pragma unroll
      for (int i = 0; i < 4; i++) {
        int S = tid + i * 256;
        int r = S >> 3, q = S & 7;
        int bo = (r * 128 + q * 16) ^ ((r & 7) << 4);
        *(float4*)(lA + bo) = *(const float4*)(arow[i] + k0 + q * 8);
      }
      // stage B: fp32 -> reg 4x4 shuffle transpose -> bf16 [n][k]
      #pragma unroll
      for (int it = 0; it < 16; it++) {
        int unit = w * 16 + it;
        int tile = unit >> 5;           // 0 = gate, 1 = up
        int kq   = (unit >> 1) & 15;
        int nh   = unit & 1;
        int krow = k0 + kq * 4 + g;
        int ncol = n0 + nh * 64 + nq * 4 + tile * INTER;
        float4 v = *(const float4*)(wbase + (size_t)krow * (2 * INTER) + ncol);
        float t0 = __shfl_xor(v.x, 32), t1 = __shfl_xor(v.y, 32);
        float t2 = __shfl_xor(v.z, 32), t3 = __shfl_xor(v.w, 32);
        bool hi2 = (g & 2) != 0;
        float a0 = hi2 ? t2 : v.x;
        float a1 = hi2 ? t3 : v.y;
        float a2 = hi2 ? v.z : t0;
        float a3 = hi2 ? v.w : t1;
        float s0 = __shfl_xor(a0, 16), s1 = __shfl_xor(a1, 16);
        float s2 = __shfl_xor(a2, 16), s3 = __shfl_xor(a3, 16);
        bool odd = (g & 1) != 0;
        float u0 = odd ? s1 : a0;
        float u1 = odd ? a1 : s0;
        float u2 = odd ? s3 : a2;
        float u3 = odd ? a3 : s2;
        bf16x4 b;
        b[0] = (__bf16)u0; b[1] = (__bf16)u1; b[2] = (__bf16)u2; b[3] = (__bf16)u3;
        int nrow = tile * 128 + nh * 64 + nq * 4 + g;
        int bo = (nrow * 128 + kq * 8) ^ ((nrow & 7) << 4);
        *(bf16x4*)(lB + bo) = b;
      }
      __syncthreads();
      #pragma unroll
      for (int kk = 0; kk < 2; kk++) {
        const int qoff = (kk * 4 + g) * 16;
        bf16x8 af[4];
        #pragma unroll
        for (int mi = 0; mi < 4; mi++) {
          int r = wx * 64 + mi * 16 + nq;
          int bo = (r * 128 + qoff) ^ ((r & 7) << 4);
          af[mi] = *(const bf16x8*)(lA + bo);
        }
        bf16x8 bg[4];
        #pragma unroll
        for (int ni = 0; ni < 4; ni++) {
          int r = wy * 64 + ni * 16 + nq;
          int bo = (r * 128 + qoff) ^ ((r & 7) << 4);
          bg[ni] = *(const bf16x8*)(lB + bo);
        }
        #pragma unroll
        for (int mi = 0; mi < 4; mi++)
          #pragma unroll
          for (int ni = 0; ni < 4; ni++)
            accg[mi][ni] = __builtin_amdgcn_mfma_f32_16x16x32_bf16(af[mi], bg[ni], accg[mi][ni], 0, 0, 0);
        bf16x8 bu[4];
        #pragma unroll
        for (int ni = 0; ni < 4; ni++) {
          int r = 128 + wy * 64 + ni * 16 + nq;
          int bo = (r * 128 + qoff) ^ ((r & 7) << 4);
          bu[ni] = *(const bf16x8*)(lB + bo);
        }
        #pragma unroll
        for (int mi = 0; mi < 4; mi++)
          #pragma unroll
          for (int ni = 0; ni < 4; ni++)
            accu[mi][ni] = __builtin_amdgcn_mfma_f32_16x16x32_bf16(af[mi], bu[ni], accu[mi][ni], 0, 0, 0);
      }
      __syncthreads();
    }

    // epilogue: h = silu(g)*u * pair_w  (bf16)
    #pragma unroll
    for (int mi = 0; mi < 4; mi++) {
      #pragma unroll
      for (int reg = 0; reg < 4; reg++) {
        int r = wx * 64 + mi * 16 + g * 4 + reg;
        if (r < rows) {
          int prow = off + m0 + r;
          float pw = pair_w[prow];
          __bf16* hrow = hbuf + (size_t)prow * INTER + n0 + wy * 64;
          #pragma unroll
          for (int ni = 0; ni < 4; ni++) {
            float gv = accg[mi][ni][reg];
            float uv = accu[mi][ni][reg];
            float sv = gv / (1.f + __expf(-gv));
            hrow[ni * 16 + nq] = (__bf16)(sv * uv * pw);
          }
        }
      }
    }
  }
}

// ---------------- grouped GEMM2: h @ Wd -> atomic scatter-add into out ----------------

__global__ __launch_bounds__(256) void gemm2_kernel(
    const __bf16* __restrict__ hbuf, const float* __restrict__ wd,
    const int* __restrict__ offsets, const int* __restrict__ pair_tok,
    float* __restrict__ out) {
  __shared__ __align__(16) char lsm[32768];
  char* lA = lsm;            // 128 x 64 bf16 swizzled
  char* lB = lsm + 16384;    // 128 x 64 bf16 swizzled

  const int e   = blockIdx.z;
  const int off = offsets[e];
  const int cnt = offsets[e + 1] - off;
  if (cnt <= 0) return;
  const int n0 = blockIdx.x * 128;
  const float* wbase = wd + (size_t)e * INTER * HID;
  const int tid  = threadIdx.x;
  const int lane = tid & 63;
  const int w    = tid >> 6;
  const int wx = w & 1, wy = w >> 1;
  const int g  = lane >> 4;
  const int nq = lane & 15;

  for (int mt = blockIdx.y; mt * 128 < cnt; mt += (int)gridDim.y) {
    const int m0   = mt * 128;
    const int rows = min(128, cnt - m0);

    const __bf16* arow[4];
    #pragma unroll
    for (int i = 0; i < 4; i++) {
      int S = tid + i * 256;
      int r = S >> 3;
      int rr = (r < rows) ? r : 0;
      arow[i] = hbuf + (size_t)(off + m0 + rr) * INTER;
    }

    f32x4 acc[4][4];
    #pragma unroll
    for (int mi = 0; mi < 4; mi++)
      #pragma unroll
      for (int ni = 0; ni < 4; ni++)
        #pragma unroll
        for (int q = 0; q < 4; q++) acc[mi][ni][q] = 0.f;

    for (int k0 = 0; k0 < INTER; k0 += 64) {   // 12 steps
      #pragma unroll
      for (int i = 0; i < 4; i++) {
        int S = tid + i * 256;
        int r = S >> 3, q = S & 7;
        int bo = (r * 128 + q * 16) ^ ((r & 7) << 4);
        *(float4*)(lA + bo) = *(const float4*)(arow[i] + k0 + q * 8);
      }
      #pragma unroll
      for (int it = 0; it < 8; it++) {
        int unit = w * 8 + it;
        int kq = unit >> 1;
        int nh = unit & 1;
        int krow = k0 + kq * 4 + g;
        int ncol = n0 + nh * 64 + nq * 4;
        float4 v = *(const float4*)(wbase + (size_t)krow * HID + ncol);
        float t0 = __shfl_xor(v.x, 32), t1 = __shfl_xor(v.y, 32);
        float t2 = __shfl_xor(v.z, 32), t3 = __shfl_xor(v.w, 32);
        bool hi2 = (g & 2) != 0;
        float a0 = hi2 ? t2 : v.x;
        float a1 = hi2 ? t3 : v.y;
        float a2 = hi2 ? v.z : t0;
        float a3 = hi2 ? v.w : t1;
        float s0 = __shfl_xor(a0, 16), s1 = __shfl_xor(a1, 16);
        float s2 = __shfl_xor(a2, 16), s3 = __shfl_xor(a3, 16);
        bool odd = (g & 1) != 0;
        float u0 = odd ? s1 : a0;
        float u1 = odd ? a1 : s0;
        float u2 = odd ? s3 : a2;
        float u3 = odd ? a3 : s2;
        bf16x4 b;
        b[0] = (__bf16)u0; b[1] = (__bf16)u1; b[2] = (__bf16)u2; b[3] = (__bf16)u3;
        int nrow = nh * 64 + nq * 4 + g;
        int bo = (nrow * 128 + kq * 8) ^ ((nrow & 7) << 4);
        *(bf16x4*)(lB + bo) = b;
      }
      __syncthreads();
      #pragma unroll
      for (int kk = 0; kk < 2; kk++) {
        const int qoff = (kk * 4 + g) * 16;
        bf16x8 af[4], bb[4];
        #pragma unroll
        for (int mi = 0; mi < 4; mi++) {
          int r = wx * 64 + mi * 16 + nq;
          int bo = (r * 128 + qoff) ^ ((r & 7) << 4);
          af[mi] = *(const bf16x8*)(lA + bo);
        }
        #pragma unroll
        for (int ni = 0; ni < 4; ni++) {
          int r = wy * 64 + ni * 16 + nq;
          int bo = (r * 128 + qoff) ^ ((r & 7) << 4);
          bb[ni] = *(const bf16x8*)(lB + bo);
        }
        #pragma unroll
        for (int mi = 0; mi < 4; mi++)
          #pragma unroll
          for (int ni = 0; ni < 4; ni++)
            acc[mi][ni] = __builtin_amdgcn_mfma_f32_16x16x32_bf16(af[mi], bb[ni], acc[mi][ni], 0, 0, 0);
      }
      __syncthreads();
    }

    #pragma unroll
    for (int mi = 0; mi < 4; mi++) {
      #pragma unroll
      for (int reg = 0; reg < 4; reg++) {
        int r = wx * 64 + mi * 16 + g * 4 + reg;
        if (r < rows) {
          int tok = pair_tok[off + m0 + r];
          float* orow = out + (size_t)tok * HID + n0 + wy * 64;
          #pragma unroll
          for (int ni = 0; ni < 4; ni++)
            atomicAdd(&orow[ni * 16 + nq], acc[mi][ni][reg]);
        }
      }
    }
  }
}

// ---------------- launch ----------------

extern "C" void kernel_launch(void* const* d_in, const int* in_sizes, int n_in,
                              void* d_out, int out_size, void* d_ws, size_t ws_size,
                              hipStream_t stream) {
  const float* x   = (const float*)d_in[0];
  const float* gw  = (const float*)d_in[1];
  const float* wgu = (const float*)d_in[2];
  const float* wd  = (const float*)d_in[3];
  float* out = (float*)d_out;

  char* ws = (char*)d_ws;
  int*   counts   = (int*)(ws + 0);
  int*   fill     = (int*)(ws + 256);
  int*   offsets  = (int*)(ws + 512);
  int*   topk_id  = (int*)(ws + 1024);
  float* topk_w   = (float*)(ws + 1024 + 131072);
  int*   pair_tok = (int*)(ws + 1024 + 262144);
  float* pair_w   = (float*)(ws + 1024 + 393216);
  __bf16* xbf  = (__bf16*)(ws + (1 << 20));
  __bf16* hbuf = (__bf16*)(ws + (1 << 20) + 16777216);

  hipMemsetAsync(d_out, 0, (size_t)out_size * sizeof(float), stream);
  zero_meta_kernel<<<1, 128, 0, stream>>>(counts, fill);
  router_kernel<<<256, 256, 0, stream>>>(x, gw, topk_id, topk_w, counts);
  scan_kernel<<<1, 64, 0, stream>>>(counts, offsets);
  scatter_kernel<<<128, 256, 0, stream>>>(topk_id, topk_w, offsets, fill, pair_tok, pair_w);
  cvt_kernel<<<(T_TOK * HID / 4) / 256, 256, 0, stream>>>(x, xbf);
  gemm1_kernel<<<dim3(6, 8, NEXP), 256, 0, stream>>>(xbf, wgu, offsets, pair_tok, pair_w, hbuf);
  gemm2_kernel<<<dim3(16, 8, NEXP), 256, 0, stream>>>(hbuf, wd, offsets, pair_tok, out);
}

// Round 2
// 1410.381 us; speedup vs baseline: 1.2617x; 1.2617x over previous
//
#include <hip/hip_runtime.h>
#include <hip/hip_bf16.h>
#include <cstdint>
#include <cstddef>

#define T_TOK 4096
#define HID   2048
#define INTER 768
#define NEXP  64

typedef float  f32x4  __attribute__((ext_vector_type(4)));
typedef __bf16 bf16x8 __attribute__((ext_vector_type(8)));
typedef __bf16 bf16x4 __attribute__((ext_vector_type(4)));

__device__ __forceinline__ void gl16(const void* g, void* l) {
  __builtin_amdgcn_global_load_lds((const __attribute__((address_space(1))) void*)g,
                                   (__attribute__((address_space(3))) void*)l, 16, 0, 0);
}

// ---------------- small helper kernels ----------------

__global__ void zero_meta_kernel(int* counts, int* fill) {
  int t = threadIdx.x;
  if (t < NEXP) { counts[t] = 0; fill[t] = 0; }
}

__global__ void scan_kernel(const int* __restrict__ counts, int* __restrict__ offsets) {
  if (threadIdx.x == 0) {
    int s = 0;
    for (int e = 0; e < NEXP; e++) { offsets[e] = s; s += counts[e]; }
    offsets[NEXP] = s;
  }
}

__global__ void scatter_kernel(const int* __restrict__ topk_id, const float* __restrict__ topk_w,
                               const int* __restrict__ offsets, int* __restrict__ fill,
                               int* __restrict__ pair_tok, float* __restrict__ pair_w) {
  int i = blockIdx.x * 256 + threadIdx.x;  // 0..32767
  int e = topk_id[i];
  int pos = offsets[e] + atomicAdd(&fill[e], 1);
  pair_tok[pos] = i >> 3;
  pair_w[pos]  = topk_w[i];
}

__global__ void cvt_kernel(const float* __restrict__ x, __bf16* __restrict__ xbf) {
  int i = blockIdx.x * 256 + threadIdx.x;  // T*H/4 threads
  float4 v = ((const float4*)x)[i];
  bf16x4 b;
  b[0] = (__bf16)v.x; b[1] = (__bf16)v.y; b[2] = (__bf16)v.z; b[3] = (__bf16)v.w;
  ((bf16x4*)xbf)[i] = b;
}

// ---------------- router: fp32 logits + wave-wide top-8 (unchanged, validated) ----------------

__global__ __launch_bounds__(256) void router_kernel(
    const float* __restrict__ x, const float* __restrict__ gw,
    int* __restrict__ topk_id, float* __restrict__ topk_w, int* __restrict__ counts) {
  __shared__ float gs[64][65];
  __shared__ float xs[16][65];
  const int tid  = threadIdx.x;
  const int lane = tid & 63;
  const int wv   = tid >> 6;
  const int tblk = blockIdx.x * 16;

  float acc[4] = {0.f, 0.f, 0.f, 0.f};
  for (int kc = 0; kc < HID; kc += 64) {
    #pragma unroll
    for (int i = 0; i < 4; i++) {
      int r = tid >> 2;
      int c = (tid & 3) * 16 + i * 4;
      float4 v = *(const float4*)(gw + (size_t)r * HID + kc + c);
      gs[r][c + 0] = v.x; gs[r][c + 1] = v.y; gs[r][c + 2] = v.z; gs[r][c + 3] = v.w;
    }
    {
      int r = tid >> 4;
      int c = (tid & 15) * 4;
      float4 v = *(const float4*)(x + (size_t)(tblk + r) * HID + kc + c);
      xs[r][c + 0] = v.x; xs[r][c + 1] = v.y; xs[r][c + 2] = v.z; xs[r][c + 3] = v.w;
    }
    __syncthreads();
    #pragma unroll 8
    for (int k = 0; k < 64; k++) {
      float g = gs[lane][k];
      #pragma unroll
      for (int j = 0; j < 4; j++) acc[j] = fmaf(xs[wv * 4 + j][k], g, acc[j]);
    }
    __syncthreads();
  }

  for (int j = 0; j < 4; j++) {
    int t = tblk + wv * 4 + j;
    float vsel = acc[j];
    float m1 = 0.f, denom = 0.f;
    int myid = 0; float myw = 0.f;
    for (int s = 0; s < 8; s++) {
      float bv = vsel; int bi = lane;
      #pragma unroll
      for (int off = 32; off > 0; off >>= 1) {
        float ov = __shfl_xor(bv, off);
        int   oi = __shfl_xor(bi, off);
        if (ov > bv || (ov == bv && oi < bi)) { bv = ov; bi = oi; }
      }
      if (s == 0) m1 = bv;
      float ev = __expf(bv - m1);
      denom += ev;
      if (lane == s)  { myid = bi; myw = ev; }
      if (lane == bi) vsel = -3.402823466e38f;
    }
    if (lane < 8) {
      topk_id[t * 8 + lane] = myid;
      topk_w[t * 8 + lane]  = myw / denom;
      atomicAdd(&counts[myid], 1);
    }
  }
}

// ---------------- weight transpose + fp32->bf16 into GEMM-native tiled layout ----------------
// src: [Echunk][Kd][Nd] fp32.  dst (16B granules): [e][nb= n/128][kt = k/64][q = k8chunk 0..7][n 0..127]
// one wave per 64x64 tile; in-reg 4x4 shfl transpose; LDS (swizzled) for write coalescing.

__global__ __launch_bounds__(256) void transpose_cvt_kernel(
    const float* __restrict__ src, __bf16* __restrict__ dst, int Kd, int Nd) {
  __shared__ __align__(16) char S[32768];
  const int tid = threadIdx.x;
  const int lane = tid & 63;
  const int wv = tid >> 6;
  char* Sw = S + wv * 8192;
  const int g = lane >> 4, nq = lane & 15;
  const int NT = Nd >> 6, KT = Kd >> 6, NB = Nd >> 7;
  int wid = blockIdx.x * 4 + wv;
  int tpe = KT * NT;
  int e = wid / tpe;
  int rem = wid - e * tpe;
  int kt = rem / NT;
  int nt = rem - kt * NT;
  const float* sp = src + ((size_t)e * Kd + (size_t)kt * 64) * Nd + nt * 64;

  float4 vv[16];
  #pragma unroll
  for (int kq = 0; kq < 16; kq++)
    vv[kq] = *(const float4*)(sp + (size_t)(kq * 4 + g) * Nd + nq * 4);

  const int n_l = nq * 4 + g;
  #pragma unroll
  for (int kq = 0; kq < 16; kq++) {
    float4 v = vv[kq];
    float t0 = __shfl_xor(v.x, 32), t1 = __shfl_xor(v.y, 32);
    float t2 = __shfl_xor(v.z, 32), t3 = __shfl_xor(v.w, 32);
    bool hi2 = (g & 2) != 0;
    float a0 = hi2 ? t2 : v.x, a1 = hi2 ? t3 : v.y;
    float a2 = hi2 ? v.z : t0, a3 = hi2 ? v.w : t1;
    float s0 = __shfl_xor(a0, 16), s1 = __shfl_xor(a1, 16);
    float s2 = __shfl_xor(a2, 16), s3 = __shfl_xor(a3, 16);
    bool odd = (g & 1) != 0;
    float u0 = odd ? s1 : a0, u1 = odd ? a1 : s0;
    float u2 = odd ? s3 : a2, u3 = odd ? a3 : s2;
    bf16x4 b; b[0] = (__bf16)u0; b[1] = (__bf16)u1; b[2] = (__bf16)u2; b[3] = (__bf16)u3;
    *(bf16x4*)(Sw + n_l * 128 + ((kq ^ (n_l & 15)) << 3)) = b;  // lane holds col n_l, k-quad kq
  }
  asm volatile("s_waitcnt lgkmcnt(0)" ::: "memory");
  __builtin_amdgcn_sched_barrier(0);
  uint4* gdst = (uint4*)dst + ((((size_t)e * NB + (nt >> 1)) * KT + kt) * 1024) + ((nt & 1) << 6) + lane;
  #pragma unroll
  for (int q = 0; q < 8; q++) {
    int p0 = (2 * q) ^ (lane & 15), p1 = (2 * q + 1) ^ (lane & 15);
    uint2 lo = *(const uint2*)(Sw + lane * 128 + (p0 << 3));
    uint2 hi = *(const uint2*)(Sw + lane * 128 + (p1 << 3));
    gdst[q * 128] = make_uint4(lo.x, lo.y, hi.x, hi.y);
  }
}

// ---------------- grouped GEMM1: x @ Wgu -> SwiGLU -> h (pair-weight folded) ----------------
// 512 threads (8 waves, 2m x 4n), BM=128, n-span 128 (gate+up each), BK=64, double-buffered gload_lds.

__global__ __launch_bounds__(512) void gemm1_kernel(
    const __bf16* __restrict__ xbf, const __bf16* __restrict__ w2gu,
    const int* __restrict__ offsets, const int* __restrict__ pair_tok,
    const float* __restrict__ pair_w, __bf16* __restrict__ hbuf, int e0) {
  __shared__ __align__(16) char smem[98304];   // 2 x (A 16K | Bg 16K | Bu 16K)
  const int ez = blockIdx.z, e = e0 + ez;
  const int off = offsets[e], cnt = offsets[e + 1] - off;
  if (cnt <= 0) return;
  const int nb = blockIdx.x;                    // 0..5
  const int tid = threadIdx.x, lane = tid & 63, w = tid >> 6;
  const int wm = w >> 2, wn = w & 3;
  const int g = lane >> 4, nq = lane & 15;
  const int q0 = tid >> 7;                      // 0..3
  const uint4* wgug = (const uint4*)w2gu + ((size_t)ez * 12 + nb) * 32768;
  const uint4* wguu = (const uint4*)w2gu + ((size_t)ez * 12 + 6 + nb) * 32768;

#define G1_STAGE(dbuf, ks_) do {                                        \
    char* bA_ = smem + (dbuf) * 49152;                                  \
    const __bf16* ap_ = arow + (ks_) * 64;                              \
    gl16(ap_ + q0 * 8,        bA_ + tid * 16);                          \
    gl16(ap_ + (q0 + 4) * 8,  bA_ + tid * 16 + 8192);                   \
    const uint4* gg_ = wgug + (size_t)(ks_) * 1024 + tid;               \
    gl16(gg_,        bA_ + 16384 + tid * 16);                           \
    gl16(gg_ + 512,  bA_ + 16384 + tid * 16 + 8192);                    \
    const uint4* gu_ = wguu + (size_t)(ks_) * 1024 + tid;               \
    gl16(gu_,        bA_ + 32768 + tid * 16);                           \
    gl16(gu_ + 512,  bA_ + 32768 + tid * 16 + 8192);                    \
  } while (0)

  for (int mt = blockIdx.y; mt * 128 < cnt; mt += (int)gridDim.y) {
    const int m0 = mt * 128;
    const int rows = min(128, cnt - m0);
    const int r = tid & 127;
    const int rr = (r < rows) ? r : 0;
    const __bf16* arow = xbf + (size_t)pair_tok[off + m0 + rr] * HID;

    f32x4 accg[4][2], accu[4][2];
    #pragma unroll
    for (int mi = 0; mi < 4; mi++)
      #pragma unroll
      for (int ni = 0; ni < 2; ni++)
        #pragma unroll
        for (int q = 0; q < 4; q++) { accg[mi][ni][q] = 0.f; accu[mi][ni][q] = 0.f; }

    G1_STAGE(0, 0);
    __syncthreads();
    int cur = 0;
    for (int ks = 0; ks < 32; ks++) {
      if (ks + 1 < 32) G1_STAGE(cur ^ 1, ks + 1);
      {
        char* bA = smem + cur * 49152;
        char* bG = bA + 16384;
        char* bU = bA + 32768;
        #pragma unroll
        for (int kk = 0; kk < 2; kk++) {
          const int q = kk * 4 + g;
          bf16x8 af[4], bg[2], bu[2];
          #pragma unroll
          for (int mi = 0; mi < 4; mi++)
            af[mi] = *(const bf16x8*)(bA + q * 2048 + (wm * 64 + mi * 16 + nq) * 16);
          #pragma unroll
          for (int ni = 0; ni < 2; ni++) {
            bg[ni] = *(const bf16x8*)(bG + q * 2048 + (wn * 32 + ni * 16 + nq) * 16);
            bu[ni] = *(const bf16x8*)(bU + q * 2048 + (wn * 32 + ni * 16 + nq) * 16);
          }
          #pragma unroll
          for (int mi = 0; mi < 4; mi++)
            #pragma unroll
            for (int ni = 0; ni < 2; ni++) {
              accg[mi][ni] = __builtin_amdgcn_mfma_f32_16x16x32_bf16(af[mi], bg[ni], accg[mi][ni], 0, 0, 0);
              accu[mi][ni] = __builtin_amdgcn_mfma_f32_16x16x32_bf16(af[mi], bu[ni], accu[mi][ni], 0, 0, 0);
            }
        }
      }
      __syncthreads();
      cur ^= 1;
    }

    // epilogue: h = silu(g)*u * pair_w  (bf16)
    #pragma unroll
    for (int mi = 0; mi < 4; mi++) {
      #pragma unroll
      for (int reg = 0; reg < 4; reg++) {
        int rrow = wm * 64 + mi * 16 + g * 4 + reg;
        if (rrow < rows) {
          int prow = off + m0 + rrow;
          float pw = pair_w[prow];
          __bf16* hrow = hbuf + (size_t)prow * INTER + nb * 128 + wn * 32;
          #pragma unroll
          for (int ni = 0; ni < 2; ni++) {
            float gv = accg[mi][ni][reg];
            float uv = accu[mi][ni][reg];
            float sv = gv / (1.f + __expf(-gv));
            hrow[ni * 16 + nq] = (__bf16)(sv * uv * pw);
          }
        }
      }
    }
  }
#undef G1_STAGE
}

// ---------------- grouped GEMM2: h @ Wd -> atomic scatter-add into out ----------------

__global__ __launch_bounds__(512) void gemm2_kernel(
    const __bf16* __restrict__ hbuf, const __bf16* __restrict__ w2d,
    const int* __restrict__ offsets, const int* __restrict__ pair_tok,
    float* __restrict__ out, int e0) {
  __shared__ __align__(16) char smem[65536];   // 2 x (A 16K | B 16K)
  const int ez = blockIdx.z, e = e0 + ez;
  const int off = offsets[e], cnt = offsets[e + 1] - off;
  if (cnt <= 0) return;
  const int nb = blockIdx.x;                    // 0..15
  const int tid = threadIdx.x, lane = tid & 63, w = tid >> 6;
  const int wm = w >> 2, wn = w & 3;
  const int g = lane >> 4, nq = lane & 15;
  const int q0 = tid >> 7;
  const uint4* wb = (const uint4*)w2d + ((size_t)ez * 16 + nb) * 12288;

#define G2_STAGE(dbuf, ks_) do {                                        \
    char* bA_ = smem + (dbuf) * 32768;                                  \
    const __bf16* ap_ = arow + (ks_) * 64;                              \
    gl16(ap_ + q0 * 8,        bA_ + tid * 16);                          \
    gl16(ap_ + (q0 + 4) * 8,  bA_ + tid * 16 + 8192);                   \
    const uint4* gb_ = wb + (size_t)(ks_) * 1024 + tid;                 \
    gl16(gb_,        bA_ + 16384 + tid * 16);                           \
    gl16(gb_ + 512,  bA_ + 16384 + tid * 16 + 8192);                    \
  } while (0)

  for (int mt = blockIdx.y; mt * 128 < cnt; mt += (int)gridDim.y) {
    const int m0 = mt * 128;
    const int rows = min(128, cnt - m0);
    const int r = tid & 127;
    const int rr = (r < rows) ? r : 0;
    const __bf16* arow = hbuf + (size_t)(off + m0 + rr) * INTER;

    f32x4 acc[4][2];
    #pragma unroll
    for (int mi = 0; mi < 4; mi++)
      #pragma unroll
      for (int ni = 0; ni < 2; ni++)
        #pragma unroll
        for (int q = 0; q < 4; q++) acc[mi][ni][q] = 0.f;

    G2_STAGE(0, 0);
    __syncthreads();
    int cur = 0;
    for (int ks = 0; ks < 12; ks++) {
      if (ks + 1 < 12) G2_STAGE(cur ^ 1, ks + 1);
      {
        char* bA = smem + cur * 32768;
        char* bB = bA + 16384;
        #pragma unroll
        for (int kk = 0; kk < 2; kk++) {
          const int q = kk * 4 + g;
          bf16x8 af[4], bb[2];
          #pragma unroll
          for (int mi = 0; mi < 4; mi++)
            af[mi] = *(const bf16x8*)(bA + q * 2048 + (wm * 64 + mi * 16 + nq) * 16);
          #pragma unroll
          for (int ni = 0; ni < 2; ni++)
            bb[ni] = *(const bf16x8*)(bB + q * 2048 + (wn * 32 + ni * 16 + nq) * 16);
          #pragma unroll
          for (int mi = 0; mi < 4; mi++)
            #pragma unroll
            for (int ni = 0; ni < 2; ni++)
              acc[mi][ni] = __builtin_amdgcn_mfma_f32_16x16x32_bf16(af[mi], bb[ni], acc[mi][ni], 0, 0, 0);
        }
      }
      __syncthreads();
      cur ^= 1;
    }

    #pragma unroll
    for (int mi = 0; mi < 4; mi++) {
      #pragma unroll
      for (int reg = 0; reg < 4; reg++) {
        int rrow = wm * 64 + mi * 16 + g * 4 + reg;
        if (rrow < rows) {
          int tok = pair_tok[off + m0 + rrow];
          float* orow = out + (size_t)tok * HID + nb * 128 + wn * 32;
          #pragma unroll
          for (int ni = 0; ni < 2; ni++)
            atomicAdd(&orow[ni * 16 + nq], acc[mi][ni][reg]);
        }
      }
    }
  }
#undef G2_STAGE
}

// ---------------- launch ----------------

extern "C" void kernel_launch(void* const* d_in, const int* in_sizes, int n_in,
                              void* d_out, int out_size, void* d_ws, size_t ws_size,
                              hipStream_t stream) {
  const float* x   = (const float*)d_in[0];
  const float* gw  = (const float*)d_in[1];
  const float* wgu = (const float*)d_in[2];
  const float* wd  = (const float*)d_in[3];
  float* out = (float*)d_out;

  char* ws = (char*)d_ws;
  int*   counts   = (int*)(ws + 0);
  int*   fill     = (int*)(ws + 256);
  int*   offsets  = (int*)(ws + 512);
  int*   topk_id  = (int*)(ws + 1024);
  float* topk_w   = (float*)(ws + 1024 + 131072);
  int*   pair_tok = (int*)(ws + 1024 + 262144);
  float* pair_w   = (float*)(ws + 1024 + 393216);
  __bf16* xbf  = (__bf16*)(ws + (1 << 20));
  __bf16* hbuf = (__bf16*)(ws + (1 << 20) + 16777216);
  const size_t fixed_end = (1ull << 20) + 16777216ull + 50331648ull;  // 68157440

  // choose expert-chunk size so tiled-weight workspace fits ws_size
  int EC = 1;
  const int cands[7] = {64, 32, 16, 8, 4, 2, 1};
  for (int i = 0; i < 7; i++) {
    if (fixed_end + (size_t)cands[i] * 9437184ull <= ws_size) { EC = cands[i]; break; }
  }
  const int nchunk = NEXP / EC;
  __bf16* w2gu = (__bf16*)(ws + fixed_end);
  __bf16* w2d  = (__bf16*)(ws + fixed_end + (size_t)EC * 6291456ull);

  hipMemsetAsync(d_out, 0, (size_t)out_size * sizeof(float), stream);
  zero_meta_kernel<<<1, 128, 0, stream>>>(counts, fill);
  router_kernel<<<256, 256, 0, stream>>>(x, gw, topk_id, topk_w, counts);
  scan_kernel<<<1, 64, 0, stream>>>(counts, offsets);
  scatter_kernel<<<128, 256, 0, stream>>>(topk_id, topk_w, offsets, fill, pair_tok, pair_w);
  cvt_kernel<<<(T_TOK * HID / 4) / 256, 256, 0, stream>>>(x, xbf);

  for (int c = 0; c < nchunk; c++) {
    int e0 = c * EC;
    transpose_cvt_kernel<<<EC * 192, 256, 0, stream>>>(
        wgu + (size_t)e0 * HID * (2 * INTER), w2gu, HID, 2 * INTER);
    transpose_cvt_kernel<<<EC * 96, 256, 0, stream>>>(
        wd + (size_t)e0 * INTER * HID, w2d, INTER, HID);
    gemm1_kernel<<<dim3(6, 4, EC), 512, 0, stream>>>(xbf, w2gu, offsets, pair_tok, pair_w, hbuf, e0);
    gemm2_kernel<<<dim3(16, 4, EC), 512, 0, stream>>>(hbuf, w2d, offsets, pair_tok, out, e0);
  }
}